// Round 2
// baseline (127.191 us; speedup 1.0000x reference)
//
#include <hip/hip_runtime.h>

// Gated pair-bias attention (AlphaFold-style), MI355X gfx950.
// B=8 S=1024 D=256 H=8 DH=32. All GEMM-shaped work in bf16 MFMA 16x16x32.
//
// Pipeline:
//   proj_kernel   : qh=(q Wq^T)*norm, sig=sigmoid(q Wg^T + bg), kh=k Wk^T,
//                   vhT = (v Wv^T)^T per (b,h)  [dh][s]               (bf16 in ws)
//   attn_kernel   : flash attention, swapped-operand form (S^T and O^T),
//                   zero barriers, lane-local softmax state            (bf16 in ws)
//   outproj_kernel: out = og Wo^T  (fp32 to d_out)

typedef __attribute__((ext_vector_type(4))) float f32x4;
typedef __attribute__((ext_vector_type(8))) unsigned short u16x8;
typedef __attribute__((ext_vector_type(4))) unsigned short u16x4;
typedef __attribute__((ext_vector_type(8))) __bf16 bf16x8;
typedef __attribute__((ext_vector_type(4))) __bf16 bf16x4;

#define BB 8
#define SS 1024
#define DD 256
#define HH 8
#define DHD 32

__device__ __forceinline__ float b2f(unsigned short s) {
  unsigned u = ((unsigned)s) << 16;
  return __builtin_bit_cast(float, u);
}
__device__ __forceinline__ f32x4 mfma16(u16x8 a, u16x8 b, f32x4 c) {
  return __builtin_amdgcn_mfma_f32_16x16x32_bf16(
      __builtin_bit_cast(bf16x8, a), __builtin_bit_cast(bf16x8, b), c, 0, 0, 0);
}

// ---------------------------------------------------------------------------
// Projections: C[8192,256] = A[8192,256] * W[256,256]^T  (einsum bsd,ed->bse)
// grid (128 row-tiles, 4 col-tiles, 4 slots), 256 threads (4 waves).
// Tile 64x64, K-step 32. LDS chunks (16B) XOR-swizzled: chunk ^= (row>>1)&3.
// slot 3 (v) stores TRANSPOSED per (b,h): vhT[((b*H+h)*DH+dh)*S + s].
// ---------------------------------------------------------------------------
__global__ __launch_bounds__(256) void proj_kernel(
    const float* __restrict__ q, const float* __restrict__ k,
    const float* __restrict__ v,
    const float* __restrict__ Wq, const float* __restrict__ Wg,
    const float* __restrict__ Wk, const float* __restrict__ Wv,
    const float* __restrict__ bg,
    unsigned short* __restrict__ qh, unsigned short* __restrict__ kh,
    unsigned short* __restrict__ vhT, unsigned short* __restrict__ sig) {
  const int slot = blockIdx.z;
  const float* A = (slot <= 1) ? q : (slot == 2 ? k : v);
  const float* W = (slot == 0) ? Wq : (slot == 1 ? Wg : (slot == 2 ? Wk : Wv));
  const int row0 = blockIdx.x * 64, col0 = blockIdx.y * 64;
  const int tid = threadIdx.x;
  const int w = tid >> 6, lane = tid & 63, g = lane >> 4, c = lane & 15;
  const int sr = tid >> 2, sc = tid & 3;   // staging: row 0..63, chunk 0..3

  __shared__ alignas(16) unsigned short As[64 * 32];
  __shared__ alignas(16) unsigned short Ws[64 * 32];

  const f32x4 zero = {0.f, 0.f, 0.f, 0.f};
  f32x4 acc[4] = {zero, zero, zero, zero};

  for (int kk = 0; kk < 8; ++kk) {
    __syncthreads();
    {
      const float* ap = A + (size_t)(row0 + sr) * DD + kk * 32 + sc * 8;
      f32x4 f0 = *(const f32x4*)ap;
      f32x4 f1 = *(const f32x4*)(ap + 4);
      bf16x8 a8;
#pragma unroll
      for (int j = 0; j < 4; ++j) { a8[j] = (__bf16)f0[j]; a8[j + 4] = (__bf16)f1[j]; }
      ((u16x8*)As)[sr * 4 + (sc ^ ((sr >> 1) & 3))] = __builtin_bit_cast(u16x8, a8);

      const float* wp = W + (size_t)(col0 + sr) * DD + kk * 32 + sc * 8;
      f32x4 w0 = *(const f32x4*)wp;
      f32x4 w1 = *(const f32x4*)(wp + 4);
      bf16x8 w8;
#pragma unroll
      for (int j = 0; j < 4; ++j) { w8[j] = (__bf16)w0[j]; w8[j + 4] = (__bf16)w1[j]; }
      ((u16x8*)Ws)[sr * 4 + (sc ^ ((sr >> 1) & 3))] = __builtin_bit_cast(u16x8, w8);
    }
    __syncthreads();
    const int arow = 16 * w + c;
    u16x8 af = ((u16x8*)As)[arow * 4 + (g ^ ((arow >> 1) & 3))];
#pragma unroll
    for (int n = 0; n < 4; ++n) {
      const int brow = 16 * n + c;
      u16x8 wf = ((u16x8*)Ws)[brow * 4 + (g ^ ((brow >> 1) & 3))];
      acc[n] = mfma16(af, wf, acc[n]);
    }
  }

  // D layout: row = 4*(lane>>4)+r, col = lane&15 (m89-verified)
  if (slot == 3) {
    // transposed store: vhT[(b*256 + col)*1024 + s], rows r are consecutive s
    const int row_base = row0 + 16 * w + 4 * g;
    const int bb = row_base >> 10;
    const int s0 = row_base & 1023;
#pragma unroll
    for (int n = 0; n < 4; ++n) {
      const int col = col0 + 16 * n + c;
      bf16x4 pv;
#pragma unroll
      for (int r = 0; r < 4; ++r) pv[r] = (__bf16)acc[n][r];
      *(u16x4*)(vhT + (size_t)(bb * 256 + col) * SS + s0) =
          __builtin_bit_cast(u16x4, pv);
    }
  } else {
#pragma unroll
    for (int n = 0; n < 4; ++n) {
#pragma unroll
      for (int r = 0; r < 4; ++r) {
        const int row = row0 + 16 * w + 4 * g + r;
        const int col = col0 + 16 * n + c;
        const size_t idx = (size_t)row * DD + col;
        const float val = acc[n][r];
        if (slot == 0)
          qh[idx] = __builtin_bit_cast(unsigned short,
                        (__bf16)(val * 0.17677669529663687f));  // DH^-0.5
        else if (slot == 1)
          sig[idx] = __builtin_bit_cast(unsigned short,
                         (__bf16)(1.0f / (1.0f + __expf(-(val + bg[col])))));
        else
          kh[idx] = __builtin_bit_cast(unsigned short, (__bf16)val);
      }
    }
  }
}

// ---------------------------------------------------------------------------
// Flash attention, swapped-operand form. grid (16 q-tiles, H, B), 4 waves.
// Wave w owns q rows [qt*64 + 16w, +16); lane's q = base + (lane&15).
// S^T = mfma(K, Q): lane holds S[q=c][kv=16t+4g+r] -> softmax state lane-local.
// O^T = mfma(V^T, P^T): acc[dt][r] = O^T[dh=16dt+4g+r][q=c].
// K and V^T fragments load straight from global (L1/L2-hot); only P round-
// trips through per-wave LDS (XOR-swizzled, conflict-free). ZERO barriers.
// ---------------------------------------------------------------------------
__global__ __launch_bounds__(256) void attn_kernel(
    const unsigned short* __restrict__ qh, const unsigned short* __restrict__ kh,
    const unsigned short* __restrict__ vhT, const unsigned short* __restrict__ sig,
    const float* __restrict__ mask, const float* __restrict__ bias,
    unsigned short* __restrict__ og) {
  const int qt = blockIdx.x, h = blockIdx.y, b = blockIdx.z;
  const int tid = threadIdx.x;
  const int w = tid >> 6, lane = tid & 63, g = lane >> 4, c = lane & 15;

  __shared__ alignas(16) unsigned short Ps[4][16 * 64];  // per-wave P tile
  unsigned short* P = Ps[w];

  const int q0 = qt * 64 + w * 16;
  // Q fragment (B operand): B[col=c][k=8g+i] = Q[q0+c][dh=8g+i]
  const u16x8 qf =
      *(const u16x8*)(qh + (size_t)(b * SS + q0 + c) * DD + h * DHD + g * 8);

  const f32x4 zero = {0.f, 0.f, 0.f, 0.f};
  f32x4 acc[2] = {zero, zero};
  float m_r = -1e30f, l_r = 0.f;    // softmax state for q = q0+c (lane-local)

  const float* maskb = mask + b * SS;
  const float* biasb = bias + (size_t)(h * SS + q0 + c) * SS;
  const unsigned short* kbase = kh + (size_t)(b * SS) * DD + h * DHD + g * 8;
  const unsigned short* vbase =
      vhT + (size_t)((b * HH + h) * DHD + c) * SS + g * 8;

  for (int kt = 0; kt < 16; ++kt) {
    const int kv0 = kt * 64;
    // S^T tile: sv[t][r] = S[q=c][kv=kv0+16t+4g+r]
    f32x4 sv[4];
#pragma unroll
    for (int t = 0; t < 4; ++t) {
      u16x8 kf = *(const u16x8*)(kbase + (size_t)(kv0 + 16 * t + c) * DD);
      sv[t] = mfma16(kf, qf, zero);
    }
    // + mask + pair bias (vector f32x4 loads)
#pragma unroll
    for (int t = 0; t < 4; ++t) {
      const f32x4 bi = *(const f32x4*)(biasb + kv0 + 16 * t + 4 * g);
      const f32x4 mk = *(const f32x4*)(maskb + kv0 + 16 * t + 4 * g);
#pragma unroll
      for (int r = 0; r < 4; ++r) sv[t][r] += mk[r] + bi[r];
    }
    // online softmax: 15 local max + 2 shfl, exp, 15 local add + 2 shfl
    float mx = fmaxf(fmaxf(sv[0][0], sv[0][1]), fmaxf(sv[0][2], sv[0][3]));
#pragma unroll
    for (int t = 1; t < 4; ++t)
      mx = fmaxf(mx, fmaxf(fmaxf(sv[t][0], sv[t][1]), fmaxf(sv[t][2], sv[t][3])));
    mx = fmaxf(mx, __shfl_xor(mx, 16));
    mx = fmaxf(mx, __shfl_xor(mx, 32));
    const float mnew = fmaxf(m_r, mx);
    const float scale = __expf(m_r - mnew);
    float ps = 0.f;
#pragma unroll
    for (int t = 0; t < 4; ++t)
#pragma unroll
      for (int r = 0; r < 4; ++r) {
        const float p = __expf(sv[t][r] - mnew);
        sv[t][r] = p;
        ps += p;
      }
    ps += __shfl_xor(ps, 16);
    ps += __shfl_xor(ps, 32);
    l_r = l_r * scale + ps;
    m_r = mnew;
    acc[0] *= scale;
    acc[1] *= scale;
    // P -> per-wave LDS, 16B-chunk XOR swizzle (conflict-free b64 wr/b128 rd)
#pragma unroll
    for (int t = 0; t < 4; ++t) {
      bf16x4 pv;
#pragma unroll
      for (int r = 0; r < 4; ++r) pv[r] = (__bf16)sv[t][r];
      const int n = 2 * t + (g >> 1);
      *(u16x4*)(P + c * 64 + ((n ^ (c & 7)) << 3) + ((g & 1) << 2)) =
          __builtin_bit_cast(u16x4, pv);
    }
    // O^T += V^T P^T  (wave-internal LDS RAW; compiler inserts lgkmcnt)
#pragma unroll
    for (int s2 = 0; s2 < 2; ++s2) {
      const u16x8 pf =
          *(const u16x8*)(P + c * 64 + (((4 * s2 + g) ^ (c & 7)) << 3));
#pragma unroll
      for (int dt = 0; dt < 2; ++dt) {
        const u16x8 vf =
            *(const u16x8*)(vbase + (size_t)(16 * dt) * SS + kv0 + 32 * s2);
        acc[dt] = mfma16(vf, pf, acc[dt]);
      }
    }
  }

  // epilogue: normalize, gate, store (b64-packed; dh = 16dt+4g+r consecutive r)
  const float inv = 1.0f / l_r;
#pragma unroll
  for (int dt = 0; dt < 2; ++dt) {
    const size_t idx =
        (size_t)(b * SS + q0 + c) * DD + h * DHD + 16 * dt + 4 * g;
    const u16x4 sg = *(const u16x4*)(sig + idx);
    bf16x4 ov;
#pragma unroll
    for (int r = 0; r < 4; ++r) ov[r] = (__bf16)(acc[dt][r] * inv * b2f(sg[r]));
    *(u16x4*)(og + idx) = __builtin_bit_cast(u16x4, ov);
  }
}

// ---------------------------------------------------------------------------
// Output projection: out[8192,256] = og[8192,256] * Wo[256,256]^T (fp32 out)
// ---------------------------------------------------------------------------
__global__ __launch_bounds__(256) void outproj_kernel(
    const unsigned short* __restrict__ og, const float* __restrict__ Wo,
    float* __restrict__ out) {
  const int row0 = blockIdx.x * 64, col0 = blockIdx.y * 64;
  const int tid = threadIdx.x;
  const int w = tid >> 6, lane = tid & 63, g = lane >> 4, c = lane & 15;
  const int sr = tid >> 2, sc = tid & 3;

  __shared__ alignas(16) unsigned short As[64 * 32];
  __shared__ alignas(16) unsigned short Ws[64 * 32];

  const f32x4 zero = {0.f, 0.f, 0.f, 0.f};
  f32x4 acc[4] = {zero, zero, zero, zero};

  for (int kk = 0; kk < 8; ++kk) {
    __syncthreads();
    {
      const unsigned short* ap = og + (size_t)(row0 + sr) * DD + kk * 32 + sc * 8;
      ((u16x8*)As)[sr * 4 + (sc ^ ((sr >> 1) & 3))] = *(const u16x8*)ap;

      const float* wp = Wo + (size_t)(col0 + sr) * DD + kk * 32 + sc * 8;
      f32x4 w0 = *(const f32x4*)wp;
      f32x4 w1 = *(const f32x4*)(wp + 4);
      bf16x8 w8;
#pragma unroll
      for (int j = 0; j < 4; ++j) { w8[j] = (__bf16)w0[j]; w8[j + 4] = (__bf16)w1[j]; }
      ((u16x8*)Ws)[sr * 4 + (sc ^ ((sr >> 1) & 3))] = __builtin_bit_cast(u16x8, w8);
    }
    __syncthreads();
    const int arow = 16 * w + c;
    u16x8 af = ((u16x8*)As)[arow * 4 + (g ^ ((arow >> 1) & 3))];
#pragma unroll
    for (int n = 0; n < 4; ++n) {
      const int brow = 16 * n + c;
      u16x8 wf = ((u16x8*)Ws)[brow * 4 + (g ^ ((brow >> 1) & 3))];
      acc[n] = mfma16(af, wf, acc[n]);
    }
  }

#pragma unroll
  for (int n = 0; n < 4; ++n) {
#pragma unroll
    for (int r = 0; r < 4; ++r) {
      const int row = row0 + 16 * w + 4 * g + r;
      const int col = col0 + 16 * n + c;
      out[(size_t)row * DD + col] = acc[n][r];
    }
  }
}

extern "C" void kernel_launch(void* const* d_in, const int* in_sizes, int n_in,
                              void* d_out, int out_size, void* d_ws,
                              size_t ws_size, hipStream_t stream) {
  const float* q    = (const float*)d_in[0];
  const float* k    = (const float*)d_in[1];
  const float* v    = (const float*)d_in[2];
  const float* mask = (const float*)d_in[3];
  const float* bias = (const float*)d_in[4];
  const float* Wq   = (const float*)d_in[5];
  const float* Wk   = (const float*)d_in[6];
  const float* Wv   = (const float*)d_in[7];
  const float* Wg   = (const float*)d_in[8];
  const float* bg   = (const float*)d_in[9];
  const float* Wo   = (const float*)d_in[10];
  float* out = (float*)d_out;

  char* ws = (char*)d_ws;
  unsigned short* qh  = (unsigned short*)(ws);               // 4 MB bf16
  unsigned short* kh  = (unsigned short*)(ws + (4u << 20));  // 4 MB
  unsigned short* vhT = (unsigned short*)(ws + (8u << 20));  // 4 MB (transposed)
  unsigned short* sig = (unsigned short*)(ws + (12u << 20)); // 4 MB
  unsigned short* og  = (unsigned short*)(ws + (16u << 20)); // 4 MB

  hipLaunchKernelGGL(proj_kernel, dim3(128, 4, 4), dim3(256), 0, stream,
                     q, k, v, Wq, Wg, Wk, Wv, bg, qh, kh, vhT, sig);
  hipLaunchKernelGGL(attn_kernel, dim3(16, HH, BB), dim3(256), 0, stream,
                     qh, kh, vhT, sig, mask, bias, og);
  hipLaunchKernelGGL(outproj_kernel, dim3(128, 4), dim3(256), 0, stream,
                     og, Wo, out);
}

// Round 4
// 77.287 us; speedup vs baseline: 1.6457x; 1.6457x over previous
//
#include <hip/hip_runtime.h>

// Gated pair-bias attention (AlphaFold-style), MI355X gfx950.
// B=8 S=1024 D=256 H=8 DH=32. All GEMM-shaped work in bf16 MFMA 16x16x32.
//
// Pipeline:
//   proj_kernel   : qh=(q Wq^T)*norm, sig=sigmoid(q Wg^T + bg), kh=k Wk^T,
//                   vhT = (v Wv^T)^T per (b,h)  [dh][s]               (bf16 in ws)
//   attn_kernel   : flash attention, swapped-operand form (S^T and O^T),
//                   lane-local softmax, LDS-staged K/V shared by 4 waves,
//                   reg-staged double buffer, XCD-grouped by head       (bf16 in ws)
//   outproj_kernel: out = og Wo^T  (fp32 to d_out)

typedef __attribute__((ext_vector_type(4))) float f32x4;
typedef __attribute__((ext_vector_type(8))) unsigned short u16x8;
typedef __attribute__((ext_vector_type(4))) unsigned short u16x4;
typedef __attribute__((ext_vector_type(8))) __bf16 bf16x8;
typedef __attribute__((ext_vector_type(4))) __bf16 bf16x4;

#define BB 8
#define SS 1024
#define DD 256
#define HH 8
#define DHD 32

__device__ __forceinline__ float b2f(unsigned short s) {
  unsigned u = ((unsigned)s) << 16;
  return __builtin_bit_cast(float, u);
}
__device__ __forceinline__ f32x4 mfma16(u16x8 a, u16x8 b, f32x4 c) {
  return __builtin_amdgcn_mfma_f32_16x16x32_bf16(
      __builtin_bit_cast(bf16x8, a), __builtin_bit_cast(bf16x8, b), c, 0, 0, 0);
}

// ---------------------------------------------------------------------------
// Projections: C[8192,256] = A[8192,256] * W[256,256]^T  (einsum bsd,ed->bse)
// grid (128 row-tiles, 4 col-tiles, 4 slots), 256 threads (4 waves).
// Tile 64x64, K-step 32. LDS chunks (16B) XOR-swizzled: chunk ^= (row>>1)&3.
// slot 3 (v) stores TRANSPOSED per (b,h): vhT[((b*H+h)*DH+dh)*S + s].
// ---------------------------------------------------------------------------
__global__ __launch_bounds__(256) void proj_kernel(
    const float* __restrict__ q, const float* __restrict__ k,
    const float* __restrict__ v,
    const float* __restrict__ Wq, const float* __restrict__ Wg,
    const float* __restrict__ Wk, const float* __restrict__ Wv,
    const float* __restrict__ bg,
    unsigned short* __restrict__ qh, unsigned short* __restrict__ kh,
    unsigned short* __restrict__ vhT, unsigned short* __restrict__ sig) {
  const int slot = blockIdx.z;
  const float* A = (slot <= 1) ? q : (slot == 2 ? k : v);
  const float* W = (slot == 0) ? Wq : (slot == 1 ? Wg : (slot == 2 ? Wk : Wv));
  const int row0 = blockIdx.x * 64, col0 = blockIdx.y * 64;
  const int tid = threadIdx.x;
  const int w = tid >> 6, lane = tid & 63, g = lane >> 4, c = lane & 15;
  const int sr = tid >> 2, sc = tid & 3;   // staging: row 0..63, chunk 0..3

  __shared__ alignas(16) unsigned short As[64 * 32];
  __shared__ alignas(16) unsigned short Ws[64 * 32];

  const f32x4 zero = {0.f, 0.f, 0.f, 0.f};
  f32x4 acc[4] = {zero, zero, zero, zero};

  for (int kk = 0; kk < 8; ++kk) {
    __syncthreads();
    {
      const float* ap = A + (size_t)(row0 + sr) * DD + kk * 32 + sc * 8;
      f32x4 f0 = *(const f32x4*)ap;
      f32x4 f1 = *(const f32x4*)(ap + 4);
      bf16x8 a8;
#pragma unroll
      for (int j = 0; j < 4; ++j) { a8[j] = (__bf16)f0[j]; a8[j + 4] = (__bf16)f1[j]; }
      ((u16x8*)As)[sr * 4 + (sc ^ ((sr >> 1) & 3))] = __builtin_bit_cast(u16x8, a8);

      const float* wp = W + (size_t)(col0 + sr) * DD + kk * 32 + sc * 8;
      f32x4 w0 = *(const f32x4*)wp;
      f32x4 w1 = *(const f32x4*)(wp + 4);
      bf16x8 w8;
#pragma unroll
      for (int j = 0; j < 4; ++j) { w8[j] = (__bf16)w0[j]; w8[j + 4] = (__bf16)w1[j]; }
      ((u16x8*)Ws)[sr * 4 + (sc ^ ((sr >> 1) & 3))] = __builtin_bit_cast(u16x8, w8);
    }
    __syncthreads();
    const int arow = 16 * w + c;
    u16x8 af = ((u16x8*)As)[arow * 4 + (g ^ ((arow >> 1) & 3))];
#pragma unroll
    for (int n = 0; n < 4; ++n) {
      const int brow = 16 * n + c;
      u16x8 wf = ((u16x8*)Ws)[brow * 4 + (g ^ ((brow >> 1) & 3))];
      acc[n] = mfma16(af, wf, acc[n]);
    }
  }

  // D layout: row = 4*(lane>>4)+r, col = lane&15 (m89-verified)
  if (slot == 3) {
    // transposed store: vhT[(b*256 + col)*1024 + s], rows r are consecutive s
    const int row_base = row0 + 16 * w + 4 * g;
    const int bb = row_base >> 10;
    const int s0 = row_base & 1023;
#pragma unroll
    for (int n = 0; n < 4; ++n) {
      const int col = col0 + 16 * n + c;
      bf16x4 pv;
#pragma unroll
      for (int r = 0; r < 4; ++r) pv[r] = (__bf16)acc[n][r];
      *(u16x4*)(vhT + (size_t)(bb * 256 + col) * SS + s0) =
          __builtin_bit_cast(u16x4, pv);
    }
  } else {
#pragma unroll
    for (int n = 0; n < 4; ++n) {
#pragma unroll
      for (int r = 0; r < 4; ++r) {
        const int row = row0 + 16 * w + 4 * g + r;
        const int col = col0 + 16 * n + c;
        const size_t idx = (size_t)row * DD + col;
        const float val = acc[n][r];
        if (slot == 0)
          qh[idx] = __builtin_bit_cast(unsigned short,
                        (__bf16)(val * 0.17677669529663687f));  // DH^-0.5
        else if (slot == 1)
          sig[idx] = __builtin_bit_cast(unsigned short,
                         (__bf16)(1.0f / (1.0f + __expf(-(val + bg[col])))));
        else
          kh[idx] = __builtin_bit_cast(unsigned short, (__bf16)val);
      }
    }
  }
}

// ---------------------------------------------------------------------------
// Flash attention, swapped-operand form. 1D grid 1024 blocks, 4 waves.
// XCD swizzle: widx = (bid&7)*128 + bid>>3; h = widx>>7  ->  each XCD owns one
// head: its 4MB bias slice + K/V slices go L2-resident.
// Wave w owns q rows [qt*64+16w, +16); lane's q = base + (lane&15).
// S^T = mfma(K, Q): lane holds S[q=c][kv=16t+4g+r] -> softmax lane-local.
// O^T = mfma(V^T, P^T): acc[dt][r] = O^T[dh=16dt+4g+r][q=c].
// K tile [64][32] and V^T tile [32][64] staged in LDS (XOR-swizzled 16B
// chunks, conflict-free), shared by 4 waves; next tile prefetched to regs
// before compute (T14 split). P round-trips per-wave LDS.
// ---------------------------------------------------------------------------
__global__ __launch_bounds__(256) void attn_kernel(
    const unsigned short* __restrict__ qh, const unsigned short* __restrict__ kh,
    const unsigned short* __restrict__ vhT, const unsigned short* __restrict__ sig,
    const float* __restrict__ mask, const float* __restrict__ bias,
    unsigned short* __restrict__ og) {
  const int bid = blockIdx.x;
  const int widx = (bid & 7) * 128 + (bid >> 3);
  const int h = widx >> 7, b = (widx >> 4) & 7, qt = widx & 15;
  const int tid = threadIdx.x;
  const int w = tid >> 6, lane = tid & 63, g = lane >> 4, c = lane & 15;

  __shared__ alignas(16) unsigned short Ks[64 * 32];     // [kv][dh] swizzled
  __shared__ alignas(16) unsigned short Vt[32 * 64];     // [dh][kv] swizzled
  __shared__ alignas(16) unsigned short Ps[4][16 * 64];  // per-wave P tile
  u16x8* Ks16 = (u16x8*)Ks;
  u16x8* Vt16 = (u16x8*)Vt;
  unsigned short* P = Ps[w];

  const int q0 = qt * 64 + w * 16;
  // Q fragment (B operand): B[col=c][k=8g+i] = Q[q0+c][dh=8g+i]
  const u16x8 qf =
      *(const u16x8*)(qh + (size_t)(b * SS + q0 + c) * DD + h * DHD + g * 8);

  const f32x4 zero = {0.f, 0.f, 0.f, 0.f};
  f32x4 acc[2] = {zero, zero};
  float m_r = -1e30f, l_r = 0.f;   // softmax state for q=q0+c (lane-local)

  const float* maskb = mask + b * SS;
  const float* biasb = bias + (size_t)(h * SS + q0 + c) * SS;

  // staging geometry (per thread, one 16B chunk of each tile)
  const int krow = tid >> 2, kj = tid & 3;   // K: 64 rows x 4 chunks
  const int vrow = tid >> 3, vj = tid & 7;   // V: 32 rows x 8 chunks
  const unsigned short* kg =
      kh + (size_t)(b * SS + krow) * DD + h * DHD + kj * 8;
  const unsigned short* vg =
      vhT + (size_t)((b * HH + h) * DHD + vrow) * SS + vj * 8;
  const int kslot = krow * 4 + (kj ^ ((krow >> 1) & 3));
  const int vslot = vrow * 8 + (vj ^ (vrow & 7));

  // prologue: stage tile 0
  Ks16[kslot] = *(const u16x8*)kg;
  Vt16[vslot] = *(const u16x8*)vg;
  __syncthreads();

  for (int kt = 0; kt < 16; ++kt) {
    const int kv0 = kt * 64;
    // issue next tile's global loads early (latency hides under compute)
    u16x8 kreg, vreg;
    if (kt < 15) {
      kreg = *(const u16x8*)(kg + (size_t)(kv0 + 64) * DD);
      vreg = *(const u16x8*)(vg + kv0 + 64);
    }

    // S^T tile: sv[t][r] = S[q=c][kv=kv0+16t+4g+r]
    f32x4 sv[4];
#pragma unroll
    for (int t = 0; t < 4; ++t) {
      const u16x8 kf = Ks16[(16 * t + c) * 4 + (g ^ ((c >> 1) & 3))];
      sv[t] = mfma16(kf, qf, zero);
    }
    // + mask + pair bias (vector f32x4 loads)
#pragma unroll
    for (int t = 0; t < 4; ++t) {
      const f32x4 bi = *(const f32x4*)(biasb + kv0 + 16 * t + 4 * g);
      const f32x4 mk = *(const f32x4*)(maskb + kv0 + 16 * t + 4 * g);
#pragma unroll
      for (int r = 0; r < 4; ++r) sv[t][r] += mk[r] + bi[r];
    }
    // online softmax: 15 local max + 2 shfl, exp, 15 local add + 2 shfl
    float mx = fmaxf(fmaxf(sv[0][0], sv[0][1]), fmaxf(sv[0][2], sv[0][3]));
#pragma unroll
    for (int t = 1; t < 4; ++t)
      mx = fmaxf(mx, fmaxf(fmaxf(sv[t][0], sv[t][1]), fmaxf(sv[t][2], sv[t][3])));
    mx = fmaxf(mx, __shfl_xor(mx, 16));
    mx = fmaxf(mx, __shfl_xor(mx, 32));
    const float mnew = fmaxf(m_r, mx);
    const float scale = __expf(m_r - mnew);
    float ps = 0.f;
#pragma unroll
    for (int t = 0; t < 4; ++t)
#pragma unroll
      for (int r = 0; r < 4; ++r) {
        const float p = __expf(sv[t][r] - mnew);
        sv[t][r] = p;
        ps += p;
      }
    ps += __shfl_xor(ps, 16);
    ps += __shfl_xor(ps, 32);
    l_r = l_r * scale + ps;
    m_r = mnew;
    acc[0] *= scale;
    acc[1] *= scale;
    // P -> per-wave LDS, 16B-chunk XOR swizzle
#pragma unroll
    for (int t = 0; t < 4; ++t) {
      bf16x4 pv;
#pragma unroll
      for (int r = 0; r < 4; ++r) pv[r] = (__bf16)sv[t][r];
      const int n = 2 * t + (g >> 1);
      *(u16x4*)(P + c * 64 + ((n ^ (c & 7)) << 3) + ((g & 1) << 2)) =
          __builtin_bit_cast(u16x4, pv);
    }
    // O^T += V^T P^T  (wave-internal LDS RAW; compiler inserts lgkmcnt)
#pragma unroll
    for (int s2 = 0; s2 < 2; ++s2) {
      const u16x8 pf =
          *(const u16x8*)(P + c * 64 + (((4 * s2 + g) ^ (c & 7)) << 3));
#pragma unroll
      for (int dt = 0; dt < 2; ++dt) {
        const u16x8 vf =
            Vt16[(16 * dt + c) * 8 + ((s2 * 4 + g) ^ (c & 7))];
        acc[dt] = mfma16(vf, pf, acc[dt]);
      }
    }
    // publish next tile to LDS
    if (kt < 15) {
      __syncthreads();            // everyone done reading Ks/Vt
      Ks16[kslot] = kreg;
      Vt16[vslot] = vreg;
      __syncthreads();            // next tile visible
    }
  }

  // epilogue: normalize, gate, store (b64-packed; dh = 16dt+4g+r)
  const float inv = 1.0f / l_r;
#pragma unroll
  for (int dt = 0; dt < 2; ++dt) {
    const size_t idx =
        (size_t)(b * SS + q0 + c) * DD + h * DHD + 16 * dt + 4 * g;
    const u16x4 sg = *(const u16x4*)(sig + idx);
    bf16x4 ov;
#pragma unroll
    for (int r = 0; r < 4; ++r) ov[r] = (__bf16)(acc[dt][r] * inv * b2f(sg[r]));
    *(u16x4*)(og + idx) = __builtin_bit_cast(u16x4, ov);
  }
}

// ---------------------------------------------------------------------------
// Output projection: out[8192,256] = og[8192,256] * Wo[256,256]^T (fp32 out)
// ---------------------------------------------------------------------------
__global__ __launch_bounds__(256) void outproj_kernel(
    const unsigned short* __restrict__ og, const float* __restrict__ Wo,
    float* __restrict__ out) {
  const int row0 = blockIdx.x * 64, col0 = blockIdx.y * 64;
  const int tid = threadIdx.x;
  const int w = tid >> 6, lane = tid & 63, g = lane >> 4, c = lane & 15;
  const int sr = tid >> 2, sc = tid & 3;

  __shared__ alignas(16) unsigned short As[64 * 32];
  __shared__ alignas(16) unsigned short Ws[64 * 32];

  const f32x4 zero = {0.f, 0.f, 0.f, 0.f};
  f32x4 acc[4] = {zero, zero, zero, zero};

  for (int kk = 0; kk < 8; ++kk) {
    __syncthreads();
    {
      const unsigned short* ap = og + (size_t)(row0 + sr) * DD + kk * 32 + sc * 8;
      ((u16x8*)As)[sr * 4 + (sc ^ ((sr >> 1) & 3))] = *(const u16x8*)ap;

      const float* wp = Wo + (size_t)(col0 + sr) * DD + kk * 32 + sc * 8;
      f32x4 w0 = *(const f32x4*)wp;
      f32x4 w1 = *(const f32x4*)(wp + 4);
      bf16x8 w8;
#pragma unroll
      for (int j = 0; j < 4; ++j) { w8[j] = (__bf16)w0[j]; w8[j + 4] = (__bf16)w1[j]; }
      ((u16x8*)Ws)[sr * 4 + (sc ^ ((sr >> 1) & 3))] = __builtin_bit_cast(u16x8, w8);
    }
    __syncthreads();
    const int arow = 16 * w + c;
    u16x8 af = ((u16x8*)As)[arow * 4 + (g ^ ((arow >> 1) & 3))];
#pragma unroll
    for (int n = 0; n < 4; ++n) {
      const int brow = 16 * n + c;
      u16x8 wf = ((u16x8*)Ws)[brow * 4 + (g ^ ((brow >> 1) & 3))];
      acc[n] = mfma16(af, wf, acc[n]);
    }
  }

#pragma unroll
  for (int n = 0; n < 4; ++n) {
#pragma unroll
    for (int r = 0; r < 4; ++r) {
      const int row = row0 + 16 * w + 4 * g + r;
      const int col = col0 + 16 * n + c;
      out[(size_t)row * DD + col] = acc[n][r];
    }
  }
}

extern "C" void kernel_launch(void* const* d_in, const int* in_sizes, int n_in,
                              void* d_out, int out_size, void* d_ws,
                              size_t ws_size, hipStream_t stream) {
  const float* q    = (const float*)d_in[0];
  const float* k    = (const float*)d_in[1];
  const float* v    = (const float*)d_in[2];
  const float* mask = (const float*)d_in[3];
  const float* bias = (const float*)d_in[4];
  const float* Wq   = (const float*)d_in[5];
  const float* Wk   = (const float*)d_in[6];
  const float* Wv   = (const float*)d_in[7];
  const float* Wg   = (const float*)d_in[8];
  const float* bg   = (const float*)d_in[9];
  const float* Wo   = (const float*)d_in[10];
  float* out = (float*)d_out;

  char* ws = (char*)d_ws;
  unsigned short* qh  = (unsigned short*)(ws);               // 4 MB bf16
  unsigned short* kh  = (unsigned short*)(ws + (4u << 20));  // 4 MB
  unsigned short* vhT = (unsigned short*)(ws + (8u << 20));  // 4 MB (transposed)
  unsigned short* sig = (unsigned short*)(ws + (12u << 20)); // 4 MB
  unsigned short* og  = (unsigned short*)(ws + (16u << 20)); // 4 MB

  hipLaunchKernelGGL(proj_kernel, dim3(128, 4, 4), dim3(256), 0, stream,
                     q, k, v, Wq, Wg, Wk, Wv, bg, qh, kh, vhT, sig);
  hipLaunchKernelGGL(attn_kernel, dim3(1024), dim3(256), 0, stream,
                     qh, kh, vhT, sig, mask, bias, og);
  hipLaunchKernelGGL(outproj_kernel, dim3(128, 4), dim3(256), 0, stream,
                     og, Wo, out);
}